// Round 4
// baseline (219.586 us; speedup 1.0000x reference)
//
#include <hip/hip_runtime.h>
#include <hip/hip_cooperative_groups.h>

namespace cg = cooperative_groups;

typedef __attribute__((ext_vector_type(8))) short bf16x8;   // 8 bf16 = 4 VGPR
typedef __attribute__((ext_vector_type(4))) float f32x4;    // MFMA acc

// Problem constants (fixed by setup_inputs)
#define BB 8
#define TC 1024
#define EE 256
#define KJ 8
#define MSEL 2048
#define V1 17
#define T1 8192
#define TTOT 24576
#define BI_TOT 16384
#define NCOLP 160        // 8 j-groups * 20 (v padded 17->20)
#define WSTRIDE 264      // K-dim stride in bf16 elems (16B-aligned rows, bank-staggered)

// scal layout (ints): [0]=globalmax [1..8]=max_b [9..16]=cnt(max)_b [17..24]=cnt(max-1)_b [33..40]=grpcnt
#define SCAL_OFF 0
#define GRP_OFF  1024                       // 8*16384 ints
#define WFT_OFF  (GRP_OFF + 524288)         // wfT bf16 [160][264]
#define B2_OFF   (WFT_OFF + NCOLP*WSTRIDE*2)// bias2 f32 [160]
#define BF0_OFF  (B2_OFF + 640)             // bf0 f32 [17]
#define WCT_OFF  (BF0_OFF + 128)            // wct bf16 [8][160][264]

__device__ __forceinline__ unsigned short f2bf(float f) {   // RTNE
    union { float f; unsigned u; } x; x.f = f;
    unsigned r = x.u + 0x7fffu + ((x.u >> 16) & 1u);
    return (unsigned short)(r >> 16);
}
__device__ __forceinline__ float bf2f(unsigned short h) {
    union { unsigned u; float f; } x; x.u = ((unsigned)h) << 16;
    return x.f;
}

__device__ __forceinline__ float blockReduceSum256(float v) {
    __shared__ float sm[4];
    #pragma unroll
    for (int d = 32; d; d >>= 1) v += __shfl_down(v, d, 64);
    int lane = threadIdx.x & 63, wid = threadIdx.x >> 6;
    if (lane == 0) sm[wid] = v;
    __syncthreads();
    float r = sm[0] + sm[1] + sm[2] + sm[3];
    __syncthreads();
    return r;
}

union SMem {
    struct { float w0s[EE * KJ]; float wls[V1 * 257]; } f;                 // P1 wfused
    struct { unsigned short b1s[32 * WSTRIDE]; unsigned short af[NCOLP * 72]; } w;  // P2 wcomb
    struct { unsigned short xs[32 * WSTRIDE]; unsigned short wts[NCOLP * 72];
             int xoffs[32]; int obase[32]; unsigned char vflag[32]; } m;   // P3 main
};

__device__ void wfused_one(int em, const float* W0, const float* Wl, unsigned short* wfT, SMem& sm) {
    __syncthreads();
    float* w0s = sm.f.w0s;
    float* wls = sm.f.wls;
    for (int idx = threadIdx.x; idx < EE * KJ; idx += 256) w0s[idx] = W0[em * EE * KJ + idx];
    for (int idx = threadIdx.x; idx < V1 * EE; idx += 256) {
        int v = idx >> 8, o = idx & 255;
        wls[v * 257 + o] = Wl[idx];
    }
    __syncthreads();
    int tid = threadIdx.x;
    if (tid < 136) {
        int j = tid / V1, v = tid - j * V1;
        float acc = 0.f;
        #pragma unroll 4
        for (int o = 0; o < EE; ++o) acc += w0s[o * KJ + j] * wls[v * 257 + o];
        wfT[(j * 20 + v) * WSTRIDE + em] = f2bf(acc);
    }
}

__device__ void main_tile(int g, int t, int cntg, const float* x, const unsigned short* wct,
                          const int* groups, const float* bias2, const float* bf0,
                          float* out, SMem& sm) {
    int tid = threadIdx.x;
    int nrows = min(32, cntg - t * 32);
    __syncthreads();                          // protect LDS reuse across tiles/phases
    if (tid < 32) {
        int flag = 0, xo = 0, ob = 0;
        if (tid < nrows) {
            int p = groups[g * BI_TOT + t * 32 + tid];
            int valid = p & 1;
            int tq = (p >> 1) & 1023;
            int bi = p >> 11;
            int b = bi >> 11;
            xo = (b * TC + tq) * EE;
            ob = bi * 136;
            flag = 1 + valid;
        }
        sm.m.xoffs[tid] = xo; sm.m.obase[tid] = ob; sm.m.vflag[tid] = (unsigned char)flag;
    }
    __syncthreads();
    {   // stage x rows f32->bf16: row = tid>>3, 8 float4 each
        int row = tid >> 3, q = tid & 7;
        const float* xp = x + sm.m.xoffs[row];
        #pragma unroll
        for (int i = 0; i < 8; ++i) {
            int f4 = q + 8 * i;
            float4 v = *(const float4*)(xp + f4 * 4);
            ushort4 pk;
            pk.x = f2bf(v.x); pk.y = f2bf(v.y); pk.z = f2bf(v.z); pk.w = f2bf(v.w);
            *(ushort4*)&sm.m.xs[row * WSTRIDE + f4 * 4] = pk;
        }
    }
    const int4* wsrc = (const int4*)wct;
    for (int idx = tid; idx < 1280; idx += 256) {   // stage W chunk 0
        int row = idx >> 3, f = idx & 7;
        ((int4*)sm.m.wts)[row * 9 + f] = wsrc[(g * NCOLP + row) * 33 + f];
    }
    __syncthreads();

    int w = tid >> 6, l = tid & 63;
    int rw = w & 1, chalf = w >> 1;
    int lr = l & 15, lq = l >> 4;
    f32x4 acc[5];
    #pragma unroll
    for (int tt = 0; tt < 5; ++tt) acc[tt] = (f32x4){0.f, 0.f, 0.f, 0.f};

    for (int ch = 0; ch < 4; ++ch) {
        if (ch) {
            __syncthreads();
            for (int idx = tid; idx < 1280; idx += 256) {
                int row = idx >> 3, f = idx & 7;
                ((int4*)sm.m.wts)[row * 9 + f] = wsrc[(g * NCOLP + row) * 33 + ch * 8 + f];
            }
            __syncthreads();
        }
        #pragma unroll
        for (int s = 0; s < 2; ++s) {
            bf16x8 afr = *(const bf16x8*)&sm.m.xs[(rw * 16 + lr) * WSTRIDE + ch * 64 + s * 32 + lq * 8];
            #pragma unroll
            for (int tt = 0; tt < 5; ++tt) {
                bf16x8 bfr = *(const bf16x8*)&sm.m.wts[((chalf * 5 + tt) * 16 + lr) * 72 + s * 32 + lq * 8];
                acc[tt] = __builtin_amdgcn_mfma_f32_16x16x32_bf16(afr, bfr, acc[tt], 0, 0, 0);
            }
        }
    }
    #pragma unroll
    for (int tt = 0; tt < 5; ++tt) {
        int col = (chalf * 5 + tt) * 16 + lr;
        int j = col / 20, v = col % 20;
        if (v < V1) {
            float bb = bias2[col] + bf0[v];
            float b0v = bf0[v];
            #pragma unroll
            for (int r = 0; r < 4; ++r) {
                int row = rw * 16 + lq * 4 + r;
                int fl = sm.m.vflag[row];
                if (fl) out[sm.m.obase[row] + j * V1 + v] = (fl == 2) ? (acc[tt][r] + bb) : b0v;
            }
        }
    }
}

__global__ __launch_bounds__(256) void k_all(
        const float* x, const int* value, const int* depth,
        const float* W1, const float* b1, const float* W0, const float* b0,
        const float* Wl, const float* bl, float* out,
        int* scal, int* groups, unsigned short* wfT, float* bias2, float* bf0,
        unsigned short* wct) {
    __shared__ SMem sm;
    __shared__ int s_red[4];
    __shared__ int s_wt[4], s_lcnt[8], s_lcnt2[8], s_lbase[8];
    cg::grid_group grid = cg::this_grid();
    int bid = blockIdx.x, tid = threadIdx.x;

    // ======== P1: wfused (248+8 double) | per-batch depth stats (8) | zero counters ========
    if (bid == 0 && tid < 8) scal[33 + tid] = 0;
    if (bid < 248) {
        wfused_one(bid, W0, Wl, wfT, sm);
        if (bid < 8) wfused_one(248 + bid, W0, Wl, wfT, sm);
    } else {
        int b = bid - 248;
        const int4* dp = (const int4*)(depth + b * TTOT);   // 6144 int4
        int m = -2147483648;
        for (int i = tid; i < 6144; i += 256) {
            int4 d = dp[i];
            m = max(max(m, max(d.x, d.y)), max(d.z, d.w));
        }
        #pragma unroll
        for (int dd = 32; dd; dd >>= 1) m = max(m, __shfl_down(m, dd, 64));
        if ((tid & 63) == 0) s_red[tid >> 6] = m;
        __syncthreads();
        int bmax = max(max(s_red[0], s_red[1]), max(s_red[2], s_red[3]));
        if (tid == 0) { atomicMax(&scal[0], bmax); scal[1 + b] = bmax; }
        int c1 = 0, c2 = 0;
        for (int i = tid; i < 6144; i += 256) {
            int4 d = dp[i];
            c1 += (d.x == bmax) + (d.y == bmax) + (d.z == bmax) + (d.w == bmax);
            c2 += (d.x == bmax - 1) + (d.y == bmax - 1) + (d.z == bmax - 1) + (d.w == bmax - 1);
        }
        int cc = (c1 << 16) + c2;           // both <= 24576, block sums fit
        #pragma unroll
        for (int dd = 32; dd; dd >>= 1) cc += __shfl_down(cc, dd, 64);
        __syncthreads();
        if ((tid & 63) == 0) s_red[tid >> 6] = cc;
        __syncthreads();
        if (tid == 0) {
            int tot = s_red[0] + s_red[1] + s_red[2] + s_red[3];
            scal[9 + b] = tot >> 16;           // count of max
            scal[17 + b] = tot & 0xffff;       // count of max-1
        }
    }
    grid.sync();

    // ======== P2: wcomb MFMA (0..63) | scan+group (64..71) | bf0 (72..88) | bias2 (89..156) ========
    if (bid < 64) {
        int g = bid >> 3;
        int e0 = (bid & 7) * 32;
        unsigned short* b1s = sm.w.b1s;
        unsigned short* af = sm.w.af;
        {   // stage B: W1 slice -> bf16, lanes consecutive in em
            int em_l = tid & 63;
            int eb = (tid >> 6) * 8;
            #pragma unroll
            for (int i = 0; i < 8; ++i) {
                int e = eb + i;
                #pragma unroll
                for (int c = 0; c < 4; ++c) {
                    int em = c * 64 + em_l;
                    b1s[e * WSTRIDE + em] = f2bf(W1[(e0 + e) * (EE * KJ) + em * KJ + g]);
                }
            }
        }
        for (int idx = tid; idx < 1280; idx += 256) {   // stage A chunk 0
            int row = idx >> 3, f = idx & 7;
            ((int4*)af)[row * 9 + f] = ((const int4*)wfT)[row * 33 + f];
        }
        __syncthreads();

        int w = tid >> 6, l = tid & 63;
        int ntile = w & 1, mhalf = w >> 1;
        int lr = l & 15, lq = l >> 4;
        f32x4 acc[5];
        #pragma unroll
        for (int t = 0; t < 5; ++t) acc[t] = (f32x4){0.f, 0.f, 0.f, 0.f};

        for (int ch = 0; ch < 4; ++ch) {
            if (ch) {
                __syncthreads();
                for (int idx = tid; idx < 1280; idx += 256) {
                    int row = idx >> 3, f = idx & 7;
                    ((int4*)af)[row * 9 + f] = ((const int4*)wfT)[row * 33 + ch * 8 + f];
                }
                __syncthreads();
            }
            #pragma unroll
            for (int s = 0; s < 2; ++s) {
                bf16x8 bfr = *(const bf16x8*)&b1s[(ntile * 16 + lr) * WSTRIDE + ch * 64 + s * 32 + lq * 8];
                #pragma unroll
                for (int t = 0; t < 5; ++t) {
                    bf16x8 afr = *(const bf16x8*)&af[((mhalf * 5 + t) * 16 + lr) * 72 + s * 32 + lq * 8];
                    acc[t] = __builtin_amdgcn_mfma_f32_16x16x32_bf16(afr, bfr, acc[t], 0, 0, 0);
                }
            }
        }
        #pragma unroll
        for (int t = 0; t < 5; ++t) {
            int m = (mhalf * 5 + t) * 16 + lq * 4;
            int n = e0 + ntile * 16 + lr;
            #pragma unroll
            for (int r = 0; r < 4; ++r)
                wct[(g * NCOLP + m + r) * WSTRIDE + n] = f2bf(acc[t][r]);
        }
    } else if (bid < 72) {
        // ---- fused scan + group scatter for batch b ----
        int b = bid - 64;
        int gmax = scal[0];
        int mb = scal[1 + b], cm = scal[9 + b], cm1 = scal[17 + b];
        int len1 = (mb == gmax) ? cm1 : ((mb == gmax - 1) ? cm : 0);
        const int* vb = value + b * TTOT;
        int t0 = tid * 32;
        unsigned mask = 0;
        #pragma unroll
        for (int k = 0; k < 32; k += 4) {
            int4 v = *(const int4*)(vb + t0 + k);
            if (t0 + k + 0 < len1 && v.x == 2) mask |= 1u << (k + 0);
            if (t0 + k + 1 < len1 && v.y == 2) mask |= 1u << (k + 1);
            if (t0 + k + 2 < len1 && v.z == 2) mask |= 1u << (k + 2);
            if (t0 + k + 3 < len1 && v.w == 2) mask |= 1u << (k + 3);
        }
        int cnt = __popc(mask);
        int inc = cnt;
        #pragma unroll
        for (int d = 1; d < 64; d <<= 1) {
            int n = __shfl_up(inc, d, 64);
            if ((tid & 63) >= d) inc += n;
        }
        int lane = tid & 63, wid = tid >> 6;
        if (lane == 63) s_wt[wid] = inc;
        if (tid < 8) { s_lcnt[tid] = 0; s_lcnt2[tid] = 0; }
        __syncthreads();
        int woff = 0;
        for (int w = 0; w < wid; ++w) woff += s_wt[w];
        int off0 = woff + inc - cnt;
        int mix1 = s_wt[0] + s_wt[1] + s_wt[2] + s_wt[3];
        int mix1c = min(mix1, MSEL);
        {   // phase A: per-group counts
            int off = off0;
            #pragma unroll
            for (int k = 0; k < 32; ++k) {
                if (mask & (1u << k)) {
                    if (off < MSEL) atomicAdd(&s_lcnt[(t0 + k) & 7], 1);
                    off++;
                }
            }
        }
        if (tid == 0 && mix1c < MSEL) atomicAdd(&s_lcnt[0], MSEL - mix1c);
        __syncthreads();
        if (tid < 8) s_lbase[tid] = atomicAdd(&scal[33 + tid], s_lcnt[tid]);
        __syncthreads();
        {   // phase B: scatter
            int off = off0;
            #pragma unroll
            for (int k = 0; k < 32; ++k) {
                if (mask & (1u << k)) {
                    if (off < MSEL) {
                        int t = t0 + k;
                        int g = t & 7;
                        int ls = atomicAdd(&s_lcnt2[g], 1);
                        groups[g * BI_TOT + s_lbase[g] + ls] =
                            ((b * MSEL + off) << 11) | ((t >> 3) << 1) | 1;
                    }
                    off++;
                }
            }
        }
        for (int i = mix1c + tid; i < MSEL; i += 256) {   // invalid (bias-only) rows -> g0
            int ls = atomicAdd(&s_lcnt2[0], 1);
            groups[s_lbase[0] + ls] = (b * MSEL + i) << 11;
        }
    } else if (bid < 89) {
        int v = bid - 72;
        float s = blockReduceSum256(b0[tid] * Wl[v * EE + tid]);
        if (tid == 0) bf0[v] = s + bl[v];
    } else if (bid < 157) {
        #pragma unroll
        for (int r = 0; r < 2; ++r) {
            int c17 = (bid - 89) * 2 + r;                 // 0..135
            int j = c17 / V1, v = c17 - j * V1;
            int colP = j * 20 + v;
            float s = blockReduceSum256(b1[tid] * bf2f(wfT[colP * WSTRIDE + tid]));
            if (tid == 0) bias2[colP] = s;
        }
    }
    grid.sync();

    // ======== P3: main grouped MFMA GEMM, persistent blocks over 32-row tiles ========
    int cntv[8], tb[9];
    tb[0] = 0;
    #pragma unroll
    for (int g = 0; g < 8; ++g) {
        cntv[g] = scal[33 + g];
        tb[g + 1] = tb[g] + ((cntv[g] + 31) >> 5);
    }
    int total = tb[8];
    for (int T = bid; T < total; T += 256) {
        int g = 0;
        while (T >= tb[g + 1]) ++g;
        main_tile(g, T - tb[g], cntv[g], x, wct, groups, bias2, bf0, out, sm);
    }
}

extern "C" void kernel_launch(void* const* d_in, const int* in_sizes, int n_in,
                              void* d_out, int out_size, void* d_ws, size_t ws_size,
                              hipStream_t stream) {
    const float* x     = (const float*)d_in[0];
    const int*   value = (const int*)d_in[1];
    const int*   depth = (const int*)d_in[2];
    // d_in[3] = pos (unused), d_in[4] = num_mix (constant 2048)
    const float* W1    = (const float*)d_in[5];
    const float* b1    = (const float*)d_in[6];
    const float* W0    = (const float*)d_in[7];
    const float* b0    = (const float*)d_in[8];
    const float* Wl    = (const float*)d_in[9];
    const float* bl    = (const float*)d_in[10];
    float* out = (float*)d_out;
    char* ws = (char*)d_ws;

    int*            scal   = (int*)(ws + SCAL_OFF);
    int*            groups = (int*)(ws + GRP_OFF);
    unsigned short* wfT    = (unsigned short*)(ws + WFT_OFF);
    float*          bias2  = (float*)(ws + B2_OFF);
    float*          bf0    = (float*)(ws + BF0_OFF);
    unsigned short* wct    = (unsigned short*)(ws + WCT_OFF);

    void* args[] = { &x, &value, &depth, &W1, &b1, &W0, &b0, &Wl, &bl, &out,
                     &scal, &groups, &wfT, &bias2, &bf0, &wct };
    hipLaunchCooperativeKernel((void*)k_all, dim3(256), dim3(256), args, 0, stream);
}

// Round 5
// 115.307 us; speedup vs baseline: 1.9044x; 1.9044x over previous
//
#include <hip/hip_runtime.h>

typedef __attribute__((ext_vector_type(8))) short bf16x8;   // 8 bf16 = 4 VGPR
typedef __attribute__((ext_vector_type(4))) float f32x4;    // MFMA acc

// Problem constants (fixed by setup_inputs)
#define BB 8
#define TC 1024
#define EE 256
#define KJ 8
#define MSEL 2048
#define V1 17
#define T1 8192
#define TTOT 24576
#define BI_TOT 16384
#define NCOLP 160        // 8 j-groups * 20 (v padded 17->20)
#define WSTRIDE 264      // K-dim stride in bf16 elems (16B-aligned rows, bank-staggered)

// scal layout (ints): [0]=globalmax [1..8]=max_b [9..16]=cnt(max)_b [17..24]=cnt(max-1)_b [33..40]=grpcnt
#define SCAL_OFF 0
#define GRP_OFF  1024                       // 8*16384 ints
#define WFT_OFF  (GRP_OFF + 524288)         // wfT bf16 [160][264]
#define B2_OFF   (WFT_OFF + NCOLP*WSTRIDE*2)// bias2 f32 [160]
#define BF0_OFF  (B2_OFF + 640)             // bf0 f32 [17]
#define WCT_OFF  (BF0_OFF + 128)            // wct bf16 [8][160][264]

__device__ __forceinline__ unsigned short f2bf(float f) {   // RTNE
    union { float f; unsigned u; } x; x.f = f;
    unsigned r = x.u + 0x7fffu + ((x.u >> 16) & 1u);
    return (unsigned short)(r >> 16);
}
__device__ __forceinline__ float bf2f(unsigned short h) {
    union { unsigned u; float f; } x; x.u = ((unsigned)h) << 16;
    return x.f;
}

__device__ __forceinline__ float blockReduceSum256(float v) {
    __shared__ float sm[4];
    #pragma unroll
    for (int d = 32; d; d >>= 1) v += __shfl_down(v, d, 64);
    int lane = threadIdx.x & 63, wid = threadIdx.x >> 6;
    if (lane == 0) sm[wid] = v;
    __syncthreads();
    float r = sm[0] + sm[1] + sm[2] + sm[3];
    __syncthreads();
    return r;
}

// ============ Dispatch 1: wfused (blocks 0..255) | depth stats (blocks 256..263) ============
__global__ __launch_bounds__(256) void k_pre(const float* W0, const float* Wl, const int* depth,
                                             unsigned short* wfT, int* scal) {
    int bid = blockIdx.x, tid = threadIdx.x;
    __shared__ float w0s[EE * KJ];
    __shared__ float wls[V1 * 257];
    __shared__ int s_red[4];
    if (bid < 256) {
        int em = bid;
        for (int idx = tid; idx < EE * KJ; idx += 256) w0s[idx] = W0[em * EE * KJ + idx];
        for (int idx = tid; idx < V1 * EE; idx += 256) {
            int v = idx >> 8, o = idx & 255;
            wls[v * 257 + o] = Wl[idx];
        }
        __syncthreads();
        if (tid < 136) {
            int j = tid / V1, v = tid - j * V1;
            float acc = 0.f;
            #pragma unroll 4
            for (int o = 0; o < EE; ++o) acc += w0s[o * KJ + j] * wls[v * 257 + o];
            wfT[(j * 20 + v) * WSTRIDE + em] = f2bf(acc);
        }
    } else {
        int b = bid - 256;
        if (b == 0 && tid < 8) scal[33 + tid] = 0;
        const int4* dp = (const int4*)(depth + b * TTOT);   // 6144 int4
        int m = -2147483648;
        for (int i = tid; i < 6144; i += 256) {
            int4 d = dp[i];
            m = max(max(m, max(d.x, d.y)), max(d.z, d.w));
        }
        #pragma unroll
        for (int dd = 32; dd; dd >>= 1) m = max(m, __shfl_down(m, dd, 64));
        if ((tid & 63) == 0) s_red[tid >> 6] = m;
        __syncthreads();
        int bmax = max(max(s_red[0], s_red[1]), max(s_red[2], s_red[3]));
        if (tid == 0) { atomicMax(&scal[0], bmax); scal[1 + b] = bmax; }
        int c1 = 0, c2 = 0;
        for (int i = tid; i < 6144; i += 256) {
            int4 d = dp[i];
            c1 += (d.x == bmax) + (d.y == bmax) + (d.z == bmax) + (d.w == bmax);
            c2 += (d.x == bmax - 1) + (d.y == bmax - 1) + (d.z == bmax - 1) + (d.w == bmax - 1);
        }
        int cc = (c1 << 16) + c2;           // both <= 24576, block sums fit
        #pragma unroll
        for (int dd = 32; dd; dd >>= 1) cc += __shfl_down(cc, dd, 64);
        __syncthreads();
        if ((tid & 63) == 0) s_red[tid >> 6] = cc;
        __syncthreads();
        if (tid == 0) {
            int tot = s_red[0] + s_red[1] + s_red[2] + s_red[3];
            scal[9 + b] = tot >> 16;           // count of max
            scal[17 + b] = tot & 0xffff;       // count of max-1
        }
    }
}

// ============ Dispatch 2: wcomb MFMA (0..63) | scan+group (64..71) | bf0 (72..88) | bias2 (89..156) ============
__global__ __launch_bounds__(256) void k_mid(
        const int* value, const float* W1, const float* b1, const float* b0,
        const float* Wl, const float* bl,
        int* scal, int* groups, const unsigned short* wfT, float* bias2, float* bf0,
        unsigned short* wct) {
    int bid = blockIdx.x, tid = threadIdx.x;
    __shared__ union {
        struct { unsigned short b1s[32 * WSTRIDE]; unsigned short af[NCOLP * 72]; } w;
    } sm;
    __shared__ int s_wt[4], s_lcnt[8], s_lcnt2[8], s_lbase[8];
    if (bid < 64) {
        int g = bid >> 3;
        int e0 = (bid & 7) * 32;
        unsigned short* b1s = sm.w.b1s;
        unsigned short* af = sm.w.af;
        {   // stage B: W1 slice -> bf16, lanes consecutive in em
            int em_l = tid & 63;
            int eb = (tid >> 6) * 8;
            #pragma unroll
            for (int i = 0; i < 8; ++i) {
                int e = eb + i;
                #pragma unroll
                for (int c = 0; c < 4; ++c) {
                    int em = c * 64 + em_l;
                    b1s[e * WSTRIDE + em] = f2bf(W1[(e0 + e) * (EE * KJ) + em * KJ + g]);
                }
            }
        }
        for (int idx = tid; idx < 1280; idx += 256) {   // stage A chunk 0
            int row = idx >> 3, f = idx & 7;
            ((int4*)af)[row * 9 + f] = ((const int4*)wfT)[row * 33 + f];
        }
        __syncthreads();

        int w = tid >> 6, l = tid & 63;
        int ntile = w & 1, mhalf = w >> 1;
        int lr = l & 15, lq = l >> 4;
        f32x4 acc[5];
        #pragma unroll
        for (int t = 0; t < 5; ++t) acc[t] = (f32x4){0.f, 0.f, 0.f, 0.f};

        for (int ch = 0; ch < 4; ++ch) {
            if (ch) {
                __syncthreads();
                for (int idx = tid; idx < 1280; idx += 256) {
                    int row = idx >> 3, f = idx & 7;
                    ((int4*)af)[row * 9 + f] = ((const int4*)wfT)[row * 33 + ch * 8 + f];
                }
                __syncthreads();
            }
            #pragma unroll
            for (int s = 0; s < 2; ++s) {
                bf16x8 bfr = *(const bf16x8*)&b1s[(ntile * 16 + lr) * WSTRIDE + ch * 64 + s * 32 + lq * 8];
                #pragma unroll
                for (int t = 0; t < 5; ++t) {
                    bf16x8 afr = *(const bf16x8*)&af[((mhalf * 5 + t) * 16 + lr) * 72 + s * 32 + lq * 8];
                    acc[t] = __builtin_amdgcn_mfma_f32_16x16x32_bf16(afr, bfr, acc[t], 0, 0, 0);
                }
            }
        }
        #pragma unroll
        for (int t = 0; t < 5; ++t) {
            int m = (mhalf * 5 + t) * 16 + lq * 4;
            int n = e0 + ntile * 16 + lr;
            #pragma unroll
            for (int r = 0; r < 4; ++r)
                wct[(g * NCOLP + m + r) * WSTRIDE + n] = f2bf(acc[t][r]);
        }
    } else if (bid < 72) {
        // ---- fused scan + group scatter for batch b ----
        int b = bid - 64;
        int gmax = scal[0];
        int mb = scal[1 + b], cm = scal[9 + b], cm1 = scal[17 + b];
        int len1 = (mb == gmax) ? cm1 : ((mb == gmax - 1) ? cm : 0);
        const int* vb = value + b * TTOT;
        int t0 = tid * 32;
        unsigned mask = 0;
        #pragma unroll
        for (int k = 0; k < 32; k += 4) {
            int4 v = *(const int4*)(vb + t0 + k);
            if (t0 + k + 0 < len1 && v.x == 2) mask |= 1u << (k + 0);
            if (t0 + k + 1 < len1 && v.y == 2) mask |= 1u << (k + 1);
            if (t0 + k + 2 < len1 && v.z == 2) mask |= 1u << (k + 2);
            if (t0 + k + 3 < len1 && v.w == 2) mask |= 1u << (k + 3);
        }
        int cnt = __popc(mask);
        int inc = cnt;
        #pragma unroll
        for (int d = 1; d < 64; d <<= 1) {
            int n = __shfl_up(inc, d, 64);
            if ((tid & 63) >= d) inc += n;
        }
        int lane = tid & 63, wid = tid >> 6;
        if (lane == 63) s_wt[wid] = inc;
        if (tid < 8) { s_lcnt[tid] = 0; s_lcnt2[tid] = 0; }
        __syncthreads();
        int woff = 0;
        for (int w = 0; w < wid; ++w) woff += s_wt[w];
        int off0 = woff + inc - cnt;
        int mix1 = s_wt[0] + s_wt[1] + s_wt[2] + s_wt[3];
        int mix1c = min(mix1, MSEL);
        {   // phase A: per-group counts
            int off = off0;
            #pragma unroll
            for (int k = 0; k < 32; ++k) {
                if (mask & (1u << k)) {
                    if (off < MSEL) atomicAdd(&s_lcnt[(t0 + k) & 7], 1);
                    off++;
                }
            }
        }
        if (tid == 0 && mix1c < MSEL) atomicAdd(&s_lcnt[0], MSEL - mix1c);
        __syncthreads();
        if (tid < 8) s_lbase[tid] = atomicAdd(&scal[33 + tid], s_lcnt[tid]);
        __syncthreads();
        {   // phase B: scatter
            int off = off0;
            #pragma unroll
            for (int k = 0; k < 32; ++k) {
                if (mask & (1u << k)) {
                    if (off < MSEL) {
                        int t = t0 + k;
                        int g = t & 7;
                        int ls = atomicAdd(&s_lcnt2[g], 1);
                        groups[g * BI_TOT + s_lbase[g] + ls] =
                            ((b * MSEL + off) << 11) | ((t >> 3) << 1) | 1;
                    }
                    off++;
                }
            }
        }
        for (int i = mix1c + tid; i < MSEL; i += 256) {   // invalid (bias-only) rows -> g0
            int ls = atomicAdd(&s_lcnt2[0], 1);
            groups[s_lbase[0] + ls] = (b * MSEL + i) << 11;
        }
    } else if (bid < 89) {
        int v = bid - 72;
        float s = blockReduceSum256(b0[tid] * Wl[v * EE + tid]);
        if (tid == 0) bf0[v] = s + bl[v];
    } else {
        #pragma unroll
        for (int r = 0; r < 2; ++r) {
            int c17 = (bid - 89) * 2 + r;                 // 0..135
            int j = c17 / V1, v = c17 - j * V1;
            int colP = j * 20 + v;
            float s = blockReduceSum256(b1[tid] * bf2f(wfT[colP * WSTRIDE + tid]));
            if (tid == 0) bias2[colP] = s;
        }
    }
}

// ============ Dispatch 3: main grouped MFMA GEMM ============
// grid 1024 = 8 groups x 128 tile slots; block loops tiles by +128 (skew-safe)
__global__ __launch_bounds__(256) void k_main(const float* x, const unsigned short* wct,
        const int* scal, const int* groups, const float* bias2, const float* bf0, float* out) {
    int g = blockIdx.x >> 7;
    int tile0 = blockIdx.x & 127;
    int cntg = scal[33 + g];

    __shared__ __align__(16) unsigned short xs[32 * WSTRIDE];    // [row][e] bf16
    __shared__ __align__(16) unsigned short wts[NCOLP * 72];     // [col][e-chunk(64)+pad]
    __shared__ int xoffs[32], obase[32];
    __shared__ unsigned char vflag[32];
    int tid = threadIdx.x;
    const int4* wsrc = (const int4*)wct;

    for (int tile = tile0; tile * 32 < cntg; tile += 128) {
        int nrows = min(32, cntg - tile * 32);
        __syncthreads();                      // protect LDS reuse across tile iterations
        if (tid < 32) {
            int flag = 0, xo = 0, ob = 0;
            if (tid < nrows) {
                int p = groups[g * BI_TOT + tile * 32 + tid];
                int valid = p & 1;
                int tq = (p >> 1) & 1023;
                int bi = p >> 11;
                int b = bi >> 11;
                xo = (b * TC + tq) * EE;
                ob = bi * 136;
                flag = 1 + valid;
            }
            xoffs[tid] = xo; obase[tid] = ob; vflag[tid] = (unsigned char)flag;
        }
        __syncthreads();
        {   // stage x rows f32->bf16: row = tid>>3, 8 float4 each
            int row = tid >> 3, q = tid & 7;
            const float* xp = x + xoffs[row];
            #pragma unroll
            for (int i = 0; i < 8; ++i) {
                int f4 = q + 8 * i;
                float4 v = *(const float4*)(xp + f4 * 4);
                ushort4 pk;
                pk.x = f2bf(v.x); pk.y = f2bf(v.y); pk.z = f2bf(v.z); pk.w = f2bf(v.w);
                *(ushort4*)&xs[row * WSTRIDE + f4 * 4] = pk;
            }
        }
        for (int idx = tid; idx < 1280; idx += 256) {    // stage W chunk 0
            int row = idx >> 3, f = idx & 7;
            ((int4*)wts)[row * 9 + f] = wsrc[(g * NCOLP + row) * 33 + f];
        }
        __syncthreads();

        int w = tid >> 6, l = tid & 63;
        int rw = w & 1, chalf = w >> 1;
        int lr = l & 15, lq = l >> 4;
        f32x4 acc[5];
        #pragma unroll
        for (int t = 0; t < 5; ++t) acc[t] = (f32x4){0.f, 0.f, 0.f, 0.f};

        for (int ch = 0; ch < 4; ++ch) {
            if (ch) {
                __syncthreads();
                for (int idx = tid; idx < 1280; idx += 256) {
                    int row = idx >> 3, f = idx & 7;
                    ((int4*)wts)[row * 9 + f] = wsrc[(g * NCOLP + row) * 33 + ch * 8 + f];
                }
                __syncthreads();
            }
            #pragma unroll
            for (int s = 0; s < 2; ++s) {
                bf16x8 afr = *(const bf16x8*)&xs[(rw * 16 + lr) * WSTRIDE + ch * 64 + s * 32 + lq * 8];
                #pragma unroll
                for (int t = 0; t < 5; ++t) {
                    bf16x8 bfr = *(const bf16x8*)&wts[((chalf * 5 + t) * 16 + lr) * 72 + s * 32 + lq * 8];
                    acc[t] = __builtin_amdgcn_mfma_f32_16x16x32_bf16(afr, bfr, acc[t], 0, 0, 0);
                }
            }
        }
        #pragma unroll
        for (int t = 0; t < 5; ++t) {
            int col = (chalf * 5 + t) * 16 + lr;
            int j = col / 20, v = col % 20;
            if (v < V1) {
                float bb = bias2[col] + bf0[v];
                float b0v = bf0[v];
                #pragma unroll
                for (int r = 0; r < 4; ++r) {
                    int row = rw * 16 + lq * 4 + r;
                    int fl = vflag[row];
                    if (fl) out[obase[row] + j * V1 + v] = (fl == 2) ? (acc[t][r] + bb) : b0v;
                }
            }
        }
    }
}

extern "C" void kernel_launch(void* const* d_in, const int* in_sizes, int n_in,
                              void* d_out, int out_size, void* d_ws, size_t ws_size,
                              hipStream_t stream) {
    const float* x     = (const float*)d_in[0];
    const int*   value = (const int*)d_in[1];
    const int*   depth = (const int*)d_in[2];
    // d_in[3] = pos (unused), d_in[4] = num_mix (constant 2048)
    const float* W1    = (const float*)d_in[5];
    const float* b1    = (const float*)d_in[6];
    const float* W0    = (const float*)d_in[7];
    const float* b0    = (const float*)d_in[8];
    const float* Wl    = (const float*)d_in[9];
    const float* bl    = (const float*)d_in[10];
    float* out = (float*)d_out;
    char* ws = (char*)d_ws;

    int*            scal   = (int*)(ws + SCAL_OFF);
    int*            groups = (int*)(ws + GRP_OFF);
    unsigned short* wfT    = (unsigned short*)(ws + WFT_OFF);
    float*          bias2  = (float*)(ws + B2_OFF);
    float*          bf0    = (float*)(ws + BF0_OFF);
    unsigned short* wct    = (unsigned short*)(ws + WCT_OFF);

    k_pre <<<dim3(264),  dim3(256), 0, stream>>>(W0, Wl, depth, wfT, scal);
    k_mid <<<dim3(157),  dim3(256), 0, stream>>>(value, W1, b1, b0, Wl, bl,
                                                 scal, groups, wfT, bias2, bf0, wct);
    k_main<<<dim3(1024), dim3(256), 0, stream>>>(x, wct, scal, groups, bias2, bf0, out);
}